// Round 2
// baseline (4269.481 us; speedup 1.0000x reference)
//
#include <hip/hip_runtime.h>
#include <hip/hip_bf16.h>
#include <math.h>

#define N_NODES 50000
#define E_EDGES 800000
#define S_DIM 128
#define V_DIM 16
#define HM 17            // message GVP dim_h / vectors-in
#define KM 161           // 128 + 16 rbf + 17 sh
#define HU 32            // update GVP vectors-in
#define KU 288           // 256 + 32 sh

#define EB 32            // edges per block
#define NB 32            // nodes per block
#define LDA2 292         // node A-tile leading dim (288 used)
#define LDF 132          // feats tile leading dim in edge kernel (bank-spread)

__device__ __forceinline__ float bf2f(unsigned short u) {
    union { unsigned int i; float f; } w; w.i = ((unsigned int)u) << 16; return w.f;
}
__device__ __forceinline__ unsigned short f2bf(float f) {
    union { float f; unsigned int i; } w; w.f = f;
    unsigned int x = w.i;
    x += 0x7fff + ((x >> 16) & 1);   // round-to-nearest-even
    return (unsigned short)(x >> 16);
}
__device__ __forceinline__ float silu_f(float x) { return x / (1.f + __expf(-x)); }
__device__ __forceinline__ float sigm_f(float x) { return 1.f / (1.f + __expf(-x)); }
// scalar dual-dtype load; branch (not ternary) so neither load is speculated OOB
__device__ __forceinline__ float ldf(const void* p, int i, int m) {
    if (m) return ((const float*)p)[i];
    return bf2f(((const unsigned short*)p)[i]);
}

// ---------------------------------------------------------------------------
// Detector: fp32 (flag=1) vs bf16 (flag=0) float inputs.
// ---------------------------------------------------------------------------
__global__ void detect_kernel(const unsigned short* __restrict__ s_us,
                              int* __restrict__ flag) {
    int t = threadIdx.x;
    int huge = 0;
    for (int k = 0; k < 16; ++k) {
        unsigned short u = s_us[2 * (t + 64 * k)];
        int e = (u >> 7) & 0xFF;
        if (e > 140) huge = 1;
    }
    if (huge) atomicOr(flag, 1);
}

// ---------------------------------------------------------------------------
// Counting sort of edges by dst: histogram -> exclusive scan -> scatter perm.
// ---------------------------------------------------------------------------
__global__ void hist_kernel(const int* __restrict__ ei, int* __restrict__ cnt) {
    int i = blockIdx.x * 256 + threadIdx.x;
    if (i < E_EDGES) atomicAdd(&cnt[ei[E_EDGES + i]], 1);
}

__global__ void scan_kernel(int* __restrict__ cnt) {
    __shared__ int buf[1024];
    __shared__ int base_s;
    const int t = threadIdx.x;
    if (t == 0) base_s = 0;
    __syncthreads();
    for (int c0 = 0; c0 < N_NODES; c0 += 1024) {
        int i = c0 + t;
        int v = (i < N_NODES) ? cnt[i] : 0;
        buf[t] = v;
        __syncthreads();
        for (int off = 1; off < 1024; off <<= 1) {
            int tmp = (t >= off) ? buf[t - off] : 0;
            __syncthreads();
            buf[t] += tmp;
            __syncthreads();
        }
        int base = base_s;
        if (i < N_NODES) cnt[i] = base + buf[t] - v;   // exclusive prefix
        __syncthreads();
        if (t == 0) base_s = base + buf[1023];
        __syncthreads();
    }
}

__global__ void scatter_kernel(const int* __restrict__ ei,
                               int* __restrict__ cnt,
                               int* __restrict__ perm) {
    int i = blockIdx.x * 256 + threadIdx.x;
    if (i < E_EDGES) {
        int d = ei[E_EDGES + i];
        int p = atomicAdd(&cnt[d], 1);
        perm[p] = i;
    }
}

// ---------------------------------------------------------------------------
// Prep kernel: per-node src-factorization.
//   P[n] = s[n] @ Wf_m[0:128]        [N][128]
//   Q[n] = v[n] @ Wh_m[0:16]         [N][17*3]  (h-major, xyz inner)
//   R[n] = Q[n] @ Wu_m               [N][16*3]  (o-major, xyz inner)
//   whwu16[o] = sum_h Wh[16][h]*Wu[h][o]   (unit-row contribution to Vu)
// All fp32 math identical to reference; only summation order differs.
// ---------------------------------------------------------------------------
__global__ __launch_bounds__(256, 4) void prep_kernel(
    const void* sP, const void* vP,
    const void* WhP, const void* WuP, const void* WfP,
    const int* __restrict__ flagp,
    float* __restrict__ Pg, float* __restrict__ Qg, float* __restrict__ Rg,
    float* __restrict__ whwu16)
{
    __shared__ float sA[NB * 132];      // s tile
    __shared__ float Wfb[16 * 128];     // Wf chunk; later qtile [32][51]
    __shared__ float vtile[NB * 48];
    __shared__ float WhS[HM * HM];
    __shared__ float WuS[HM * 16];

    const int t = threadIdx.x;
    const int n0 = blockIdx.x * NB;
    const int m = flagp[0];

    // stage Wh, Wu
    if (m) {
        const float* Wh = (const float*)WhP;
        const float* Wu = (const float*)WuP;
        for (int i = t; i < HM * HM; i += 256) WhS[i] = Wh[i];
        for (int i = t; i < HM * 16; i += 256) WuS[i] = Wu[i];
    } else {
        const unsigned short* Wh = (const unsigned short*)WhP;
        const unsigned short* Wu = (const unsigned short*)WuP;
        for (int i = t; i < HM * HM; i += 256) WhS[i] = bf2f(Wh[i]);
        for (int i = t; i < HM * 16; i += 256) WuS[i] = bf2f(Wu[i]);
    }
    // stage s tile (coalesced: consecutive nodes)
    if (m) {
        const float* sF = (const float*)sP;
        for (int idx = t; idx < NB * 32; idx += 256) {
            int ni = idx >> 5, col4 = (idx & 31) * 4;
            int n = n0 + ni;
            float* a = &sA[ni * 132 + col4];
            if (n < N_NODES) {
                float4 u = *(const float4*)(sF + (size_t)n * 128 + col4);
                a[0] = u.x; a[1] = u.y; a[2] = u.z; a[3] = u.w;
            } else { a[0] = a[1] = a[2] = a[3] = 0.f; }
        }
    } else {
        const unsigned short* sU = (const unsigned short*)sP;
        for (int idx = t; idx < NB * 32; idx += 256) {
            int ni = idx >> 5, col4 = (idx & 31) * 4;
            int n = n0 + ni;
            float* a = &sA[ni * 132 + col4];
            if (n < N_NODES) {
                ushort4 u = *(const ushort4*)(sU + (size_t)n * 128 + col4);
                a[0] = bf2f(u.x); a[1] = bf2f(u.y); a[2] = bf2f(u.z); a[3] = bf2f(u.w);
            } else { a[0] = a[1] = a[2] = a[3] = 0.f; }
        }
    }
    // stage v tile
    if (m) {
        const float* vF = (const float*)vP;
        for (int idx = t; idx < NB * 12; idx += 256) {
            int ni = idx / 12, c4 = (idx % 12) * 4;
            int n = n0 + ni;
            float* a = &vtile[ni * 48 + c4];
            if (n < N_NODES) {
                float4 u = *(const float4*)(vF + (size_t)n * 48 + c4);
                a[0] = u.x; a[1] = u.y; a[2] = u.z; a[3] = u.w;
            } else { a[0] = a[1] = a[2] = a[3] = 0.f; }
        }
    } else {
        const unsigned short* vU = (const unsigned short*)vP;
        for (int idx = t; idx < NB * 12; idx += 256) {
            int ni = idx / 12, c4 = (idx % 12) * 4;
            int n = n0 + ni;
            float* a = &vtile[ni * 48 + c4];
            if (n < N_NODES) {
                ushort4 u = *(const ushort4*)(vU + (size_t)n * 48 + c4);
                a[0] = bf2f(u.x); a[1] = bf2f(u.y); a[2] = bf2f(u.z); a[3] = bf2f(u.w);
            } else { a[0] = a[1] = a[2] = a[3] = 0.f; }
        }
    }
    __syncthreads();

    // P GEMM: K = 128 (Wf rows 0..127), thread = 2 nodes x 8 cols
    const int tj = t & 15, tn = t >> 4;
    const int nb = tn * 2;
    float acc[2][8];
    #pragma unroll
    for (int i = 0; i < 2; ++i)
        #pragma unroll
        for (int j = 0; j < 8; ++j) acc[i][j] = 0.f;

    for (int kk = 0; kk < 128; kk += 16) {
        if (m) {
            const float* WfF = (const float*)WfP;
            for (int idx = t; idx < 512; idx += 256) {
                int kt = idx >> 5, col4 = (idx & 31) * 4;
                float4 u = *(const float4*)(WfF + (size_t)(kk + kt) * 128 + col4);
                float* b = &Wfb[kt * 128 + col4];
                b[0] = u.x; b[1] = u.y; b[2] = u.z; b[3] = u.w;
            }
        } else {
            const unsigned short* WfU = (const unsigned short*)WfP;
            for (int idx = t; idx < 512; idx += 256) {
                int kt = idx >> 5, col4 = (idx & 31) * 4;
                ushort4 u = *(const ushort4*)(WfU + (size_t)(kk + kt) * 128 + col4);
                float* b = &Wfb[kt * 128 + col4];
                b[0] = bf2f(u.x); b[1] = bf2f(u.y); b[2] = bf2f(u.z); b[3] = bf2f(u.w);
            }
        }
        __syncthreads();
        for (int kt = 0; kt < 16; ++kt) {
            float a0 = sA[(nb + 0) * 132 + kk + kt];
            float a1 = sA[(nb + 1) * 132 + kk + kt];
            const float* brow = &Wfb[kt * 128 + tj];
            #pragma unroll
            for (int jj = 0; jj < 8; ++jj) {
                float b = brow[16 * jj];
                acc[0][jj] += a0 * b; acc[1][jj] += a1 * b;
            }
        }
        __syncthreads();
    }
    #pragma unroll
    for (int i = 0; i < 2; ++i) {
        int n = n0 + nb + i;
        if (n < N_NODES) {
            #pragma unroll
            for (int jj = 0; jj < 8; ++jj)
                Pg[(size_t)n * 128 + tj + 16 * jj] = acc[i][jj];
        }
    }

    // Q: [32][17][3]  (qtile reuses Wfb region; all Wfb readers are past the
    // final GEMM barrier)
    float* qtile = Wfb;
    for (int idx = t; idx < NB * 51; idx += 256) {
        int ni = idx / 51, rem = idx % 51;
        int h = rem / 3, c = rem % 3;
        float q = 0.f;
        for (int vv = 0; vv < 16; ++vv)
            q += vtile[ni * 48 + vv * 3 + c] * WhS[vv * HM + h];
        qtile[idx] = q;
        int n = n0 + ni;
        if (n < N_NODES) Qg[(size_t)n * 51 + rem] = q;
    }
    __syncthreads();
    // R = Q @ Wu : [32][16][3]
    for (int idx = t; idx < NB * 48; idx += 256) {
        int ni = idx / 48, oc = idx % 48;
        int o = oc / 3, c = oc % 3;
        float r = 0.f;
        for (int h = 0; h < HM; ++h)
            r += qtile[ni * 51 + h * 3 + c] * WuS[h * 16 + o];
        int n = n0 + ni;
        if (n < N_NODES) Rg[(size_t)n * 48 + oc] = r;
    }
    if (blockIdx.x == 0 && t < 16) {
        float a = 0.f;
        for (int h = 0; h < HM; ++h)
            a += WhS[16 * HM + h] * WuS[h * 16 + t];
        whwu16[t] = a;
    }
}

// ---------------------------------------------------------------------------
// Edge (message) kernel, src-factored: K=33 GEMM (rbf|sh) with accumulator
// initialized from P[src]; sh from Q[src] (3 fma); Vu from R[src] (1 fma).
// Segmented-reduce scatter over dst-sorted runs.
// ---------------------------------------------------------------------------
__global__ __launch_bounds__(256, 4) void edge_kernel(
    const void* xP, const void* WhP, const void* WfP,
    const void* bfP, const void* WgP, const void* bgP,
    const int* __restrict__ ei,
    const int* __restrict__ perm,
    const int* __restrict__ flagp,
    const float* __restrict__ Pg,
    const float* __restrict__ Qg,
    const float* __restrict__ Rg,
    const float* __restrict__ whwu16,
    float* __restrict__ agg_s,               // [N][128]
    float* __restrict__ agg_v)               // [N][48]
{
    __shared__ float Wb[33 * 128];       // W33 rows = Wf[128..160]; later feats [32][LDF]
    __shared__ float A33[EB * 33];       // cols 0..15 rbf, 16..32 sh
    __shared__ float Xb[2048];           // Wg [128][16]; later mv [32][48]
    __shared__ float gates[EB * 16];
    __shared__ float unitb[EB * 3];
    __shared__ float whs[16];
    __shared__ int srcb[EB], dstb[EB];

    const int t = threadIdx.x;
    const int e0 = blockIdx.x * EB;
    const int m = flagp[0];              // 1 = fp32 inputs

    // phase 0: permuted indices + whwu16 + stage W33
    if (t < EB) {
        int eid = perm[e0 + t];
        srcb[t] = ei[eid];
        dstb[t] = ei[E_EDGES + eid];
    }
    if (t < 16) whs[t] = whwu16[t];
    if (m) {
        const float* Wf = (const float*)WfP + 128 * 128;
        for (int idx = t; idx < 33 * 32; idx += 256) {
            int kt = idx >> 5, col4 = (idx & 31) * 4;
            float4 u = *(const float4*)(Wf + kt * 128 + col4);
            float* b = &Wb[kt * 128 + col4];
            b[0] = u.x; b[1] = u.y; b[2] = u.z; b[3] = u.w;
        }
    } else {
        const unsigned short* Wf = (const unsigned short*)WfP + 128 * 128;
        for (int idx = t; idx < 33 * 32; idx += 256) {
            int kt = idx >> 5, col4 = (idx & 31) * 4;
            ushort4 u = *(const ushort4*)(Wf + kt * 128 + col4);
            float* b = &Wb[kt * 128 + col4];
            b[0] = bf2f(u.x); b[1] = bf2f(u.y); b[2] = bf2f(u.z); b[3] = bf2f(u.w);
        }
    }
    __syncthreads();

    // accumulator init from P[src] (issued early; consumed in GEMM)
    const int tj = t & 15, te = t >> 4;
    const int eb = te * 2;
    float acc[2][8];
    #pragma unroll
    for (int i = 0; i < 2; ++i) {
        const float* prow = Pg + (size_t)srcb[eb + i] * 128 + tj;
        #pragma unroll
        for (int jj = 0; jj < 8; ++jj) acc[i][jj] = prow[16 * jj];
    }

    // phase 1: geometry + rbf (one thread per edge)
    if (t < EB) {
        int src = srcb[t], dst = dstb[t];
        float dxc[3]; float d2 = 0.f;
        for (int c = 0; c < 3; ++c) {
            float xs = ldf(xP, src * 3 + c, m);
            float xd = ldf(xP, dst * 3 + c, m);
            dxc[c] = xd - xs; d2 += dxc[c] * dxc[c];
        }
        float dist = sqrtf(fmaxf(d2, 1e-8f));
        float inv = 1.f / dist;
        for (int c = 0; c < 3; ++c) unitb[t * 3 + c] = dxc[c] * inv;
        for (int k = 0; k < 16; ++k) {
            float mu = (20.f / 15.f) * (float)k;
            float z = (dist - mu) * (1.f / 1.25f);
            A33[t * 33 + k] = __expf(-z * z);
        }
    }
    __syncthreads();
    // phase 1b: sh[e][h] = || Q[src][h] + unit * Wh[16][h] ||
    for (int idx = t; idx < EB * HM; idx += 256) {
        int e = idx / HM, h = idx % HM;
        float w = ldf(WhP, 16 * HM + h, m);
        const float* q = Qg + (size_t)srcb[e] * 51 + h * 3;
        float v0 = q[0] + unitb[e * 3 + 0] * w;
        float v1 = q[1] + unitb[e * 3 + 1] * w;
        float v2 = q[2] + unitb[e * 3 + 2] * w;
        A33[e * 33 + 16 + h] = sqrtf(fmaxf(v0 * v0 + v1 * v1 + v2 * v2, 1e-8f));
    }
    __syncthreads();

    // phase 2: feats GEMM, K = 33 (W33 fully staged; no chunking)
    for (int kt = 0; kt < 33; ++kt) {
        float a0 = A33[(eb + 0) * 33 + kt];
        float a1 = A33[(eb + 1) * 33 + kt];
        const float* brow = &Wb[kt * 128 + tj];
        #pragma unroll
        for (int jj = 0; jj < 8; ++jj) {
            float b = brow[16 * jj];
            acc[0][jj] += a0 * b; acc[1][jj] += a1 * b;
        }
    }
    // stage Wg -> Xb (untouched so far; overlaps GEMM tail)
    if (m) {
        const float* Wg = (const float*)WgP;
        for (int i = t; i < 2048; i += 256) Xb[i] = Wg[i];
    } else {
        const unsigned short* Wg = (const unsigned short*)WgP;
        for (int i = t; i < 2048; i += 256) Xb[i] = bf2f(Wg[i]);
    }
    __syncthreads();   // all W33 reads done -> Wb reusable
    // bias + silu -> feats into Wb [32][LDF]
    {
        float breg[8];
        #pragma unroll
        for (int jj = 0; jj < 8; ++jj) breg[jj] = ldf(bfP, tj + 16 * jj, m);
        #pragma unroll
        for (int i = 0; i < 2; ++i) {
            float* aout = &Wb[(eb + i) * LDF];
            #pragma unroll
            for (int jj = 0; jj < 8; ++jj)
                aout[tj + 16 * jj] = silu_f(acc[i][jj] + breg[jj]);
        }
    }
    __syncthreads();
    // phase 3: gates = sigmoid(feats @ Wg + bg); thread = 1 edge x 2 outputs
    {
        int e = t >> 3, o0 = (t & 7) * 2;
        float g0 = ldf(bgP, o0, m), g1 = ldf(bgP, o0 + 1, m);
        const float* fe = &Wb[e * LDF];
        for (int j = 0; j < S_DIM; ++j) {
            float f = fe[j];
            g0 += f * Xb[j * 16 + o0];
            g1 += f * Xb[j * 16 + o0 + 1];
        }
        gates[e * 16 + o0]     = sigm_f(g0);
        gates[e * 16 + o0 + 1] = sigm_f(g1);
    }
    __syncthreads();
    // phase 4: mv = gate * (R[src] + unit*whwu16) -> Xb (Wg dead)
    for (int r = 0; r < 6; ++r) {
        int idx = t + 256 * r;               // idx == e*48 + oc
        int e = idx / 48, oc = idx % 48, o = oc / 3, c = oc % 3;
        float vu = Rg[(size_t)srcb[e] * 48 + oc] + unitb[e * 3 + c] * whs[o];
        Xb[idx] = vu * gates[e * 16 + o];
    }
    __syncthreads();
    // phase 5: segmented reduction over dst runs (sorted -> few runs/block)
    if (t < 176) {
        float run = 0.f;
        int cur = dstb[0];
        if (t < 128) {
            const int col = t;
            for (int e = 0; e < EB; ++e) {
                int d = dstb[e];
                if (d != cur) {
                    atomicAdd(&agg_s[(size_t)cur * S_DIM + col], run);
                    run = 0.f; cur = d;
                }
                run += Wb[e * LDF + col];
            }
            atomicAdd(&agg_s[(size_t)cur * S_DIM + col], run);
        } else {
            const int oc = t - 128;
            for (int e = 0; e < EB; ++e) {
                int d = dstb[e];
                if (d != cur) {
                    atomicAdd(&agg_v[(size_t)cur * 48 + oc], run);
                    run = 0.f; cur = d;
                }
                run += Xb[e * 48 + oc];
            }
            atomicAdd(&agg_v[(size_t)cur * 48 + oc], run);
        }
    }
}

// ---------------------------------------------------------------------------
// Node (update) kernel: per block, 32 nodes. Update GVP + residual + LN.
// (unchanged from previous round)
// ---------------------------------------------------------------------------
__global__ __launch_bounds__(256) void node_kernel(
    const void* sP, const void* vP,
    const void* WhP, const void* WuP, const void* WfP,
    const void* bfP, const void* WgP, const void* bgP,
    const void* lngP, const void* lnbP,
    const int* __restrict__ flagp,
    const float* __restrict__ agg_s,         // [N][128]
    const float* __restrict__ agg_v,         // [N][48]
    void* outP)                              // [N*128] then [N*48]
{
    __shared__ float A2[NB * LDA2];
    __shared__ float Bs2[4096];
    __shared__ float WhWu2[HU * 16];
    __shared__ float gates2[NB * 16];
    __shared__ float WhS[HU * HU];
    __shared__ float mu_s[NB], rstd_s[NB], vn_s[NB];

    const int t = threadIdx.x;
    const int n0 = blockIdx.x * NB;
    const int m = flagp[0];

    if (m) {
        const float* Wh = (const float*)WhP;
        const float* Wu = (const float*)WuP;
        for (int i = t; i < HU * HU; i += 256) WhS[i] = Wh[i];
        for (int i = t; i < HU * 16; i += 256) gates2[i] = Wu[i];
    } else {
        const unsigned short* Wh = (const unsigned short*)WhP;
        const unsigned short* Wu = (const unsigned short*)WuP;
        for (int i = t; i < HU * HU; i += 256) WhS[i] = bf2f(Wh[i]);
        for (int i = t; i < HU * 16; i += 256) gates2[i] = bf2f(Wu[i]);
    }
    if (m) {
        const float* sF = (const float*)sP;
        for (int idx = t; idx < NB * 32; idx += 256) {
            int ni = idx >> 5, col4 = (idx & 31) * 4;
            int n = n0 + ni;
            float* a = &A2[ni * LDA2 + col4];
            if (n < N_NODES) {
                float4 u = *(const float4*)(sF + (size_t)n * 128 + col4);
                a[0] = u.x; a[1] = u.y; a[2] = u.z; a[3] = u.w;
            } else { a[0] = a[1] = a[2] = a[3] = 0.f; }
        }
    } else {
        const unsigned short* sU = (const unsigned short*)sP;
        for (int idx = t; idx < NB * 32; idx += 256) {
            int ni = idx >> 5, col4 = (idx & 31) * 4;
            int n = n0 + ni;
            float* a = &A2[ni * LDA2 + col4];
            if (n < N_NODES) {
                ushort4 u = *(const ushort4*)(sU + (size_t)n * 128 + col4);
                a[0] = bf2f(u.x); a[1] = bf2f(u.y); a[2] = bf2f(u.z); a[3] = bf2f(u.w);
            } else { a[0] = a[1] = a[2] = a[3] = 0.f; }
        }
    }
    for (int idx = t; idx < NB * 32; idx += 256) {
        int ni = idx >> 5, col4 = (idx & 31) * 4;
        int n = n0 + ni;
        float* a = &A2[ni * LDA2 + 128 + col4];
        if (n < N_NODES) {
            float4 u = *(const float4*)(agg_s + (size_t)n * 128 + col4);
            a[0] = u.x * 0.1f; a[1] = u.y * 0.1f; a[2] = u.z * 0.1f; a[3] = u.w * 0.1f;
        } else { a[0] = a[1] = a[2] = a[3] = 0.f; }
    }
    for (int idx = t; idx < NB * 96; idx += 256) {
        int ni = idx / 96, vc = idx % 96;
        int n = n0 + ni;
        float val = 0.f;
        if (n < N_NODES)
            val = (vc < 48) ? ldf(vP, n * 48 + vc, m)
                            : agg_v[(size_t)n * 48 + (vc - 48)] * 0.1f;
        Bs2[ni * 100 + vc] = val;
    }
    __syncthreads();
    for (int idx = t; idx < HU * 16; idx += 256) {
        int vv = idx / 16, o = idx % 16;
        float acc = 0.f;
        for (int h = 0; h < HU; ++h)
            acc += WhS[vv * HU + h] * gates2[h * 16 + o];
        WhWu2[idx] = acc;
    }
    for (int idx = t; idx < NB * HU; idx += 256) {
        int ni = idx / HU, h = idx % HU;
        const float* vc = &Bs2[ni * 100];
        float vh0 = 0.f, vh1 = 0.f, vh2 = 0.f;
        for (int vv = 0; vv < HU; ++vv) {
            float w = WhS[vv * HU + h];
            vh0 += vc[vv * 3 + 0] * w; vh1 += vc[vv * 3 + 1] * w; vh2 += vc[vv * 3 + 2] * w;
        }
        A2[ni * LDA2 + 256 + h] = sqrtf(fmaxf(vh0 * vh0 + vh1 * vh1 + vh2 * vh2, 1e-8f));
    }
    __syncthreads();
    float vureg[6];
    for (int r = 0; r < 6; ++r) {
        int idx = t + 256 * r;
        int ni = idx / 48, oc = idx % 48, o = oc / 3, c = oc % 3;
        const float* vc = &Bs2[ni * 100];
        float acc = 0.f;
        for (int vv = 0; vv < HU; ++vv)
            acc += vc[vv * 3 + c] * WhWu2[vv * 16 + o];
        vureg[r] = acc;
    }
    __syncthreads();

    const int tj = t & 15, tn = t >> 4;
    const int nb = tn * 2;
    float acc[2][8];
    #pragma unroll
    for (int i = 0; i < 2; ++i)
        #pragma unroll
        for (int j = 0; j < 8; ++j) acc[i][j] = 0.f;

    for (int kk = 0; kk < KU; kk += 32) {
        if (m) {
            const float* WfF = (const float*)WfP;
            for (int idx = t; idx < 32 * 32; idx += 256) {
                int kt = idx >> 5, col4 = (idx & 31) * 4;
                float4 u = *(const float4*)(WfF + (size_t)(kk + kt) * 128 + col4);
                float* b = &Bs2[kt * 128 + col4];
                b[0] = u.x; b[1] = u.y; b[2] = u.z; b[3] = u.w;
            }
        } else {
            const unsigned short* WfU = (const unsigned short*)WfP;
            for (int idx = t; idx < 32 * 32; idx += 256) {
                int kt = idx >> 5, col4 = (idx & 31) * 4;
                ushort4 u = *(const ushort4*)(WfU + (size_t)(kk + kt) * 128 + col4);
                float* b = &Bs2[kt * 128 + col4];
                b[0] = bf2f(u.x); b[1] = bf2f(u.y); b[2] = bf2f(u.z); b[3] = bf2f(u.w);
            }
        }
        __syncthreads();
        for (int kt = 0; kt < 32; ++kt) {
            float a0 = A2[(nb + 0) * LDA2 + kk + kt];
            float a1 = A2[(nb + 1) * LDA2 + kk + kt];
            const float* brow = &Bs2[kt * 128 + tj];
            #pragma unroll
            for (int jj = 0; jj < 8; ++jj) {
                float b = brow[16 * jj];
                acc[0][jj] += a0 * b; acc[1][jj] += a1 * b;
            }
        }
        __syncthreads();
    }
    float breg[8];
    #pragma unroll
    for (int jj = 0; jj < 8; ++jj) breg[jj] = ldf(bfP, tj + 16 * jj, m);
    #pragma unroll
    for (int i = 0; i < 2; ++i) {
        float* aout = &A2[(nb + i) * LDA2 + 128];
        #pragma unroll
        for (int jj = 0; jj < 8; ++jj)
            aout[tj + 16 * jj] = silu_f(acc[i][jj] + breg[jj]);
    }
    __syncthreads();
    if (m) {
        const float* Wg = (const float*)WgP;
        for (int i = t; i < 2048; i += 256) Bs2[i] = Wg[i];
    } else {
        const unsigned short* Wg = (const unsigned short*)WgP;
        for (int i = t; i < 2048; i += 256) Bs2[i] = bf2f(Wg[i]);
    }
    __syncthreads();
    for (int r = 0; r < 2; ++r) {
        int idx = t + 256 * r;
        int ni = idx / 16, o = idx % 16;
        const float* fe = &A2[ni * LDA2 + 128];
        float g = ldf(bgP, o, m);
        for (int j = 0; j < 128; ++j)
            g += fe[j] * Bs2[j * 16 + o];
        gates2[idx] = sigm_f(g);
    }
    __syncthreads();
    for (int r = 0; r < 6; ++r) {
        int idx = t + 256 * r;
        int ni = idx / 48, oc = idx % 48, o = oc / 3;
        int n = n0 + ni;
        float vres = 0.f;
        if (n < N_NODES)
            vres = ldf(vP, n * 48 + oc, m) + vureg[r] * gates2[ni * 16 + o];
        Bs2[ni * 48 + oc] = vres;
    }
    __syncthreads();
    if (t < NB) {
        const float* arow = &A2[t * LDA2];
        float sum = 0.f, sumsq = 0.f;
        for (int j = 0; j < 128; ++j) {
            float xr = arow[j] + arow[128 + j];
            sum += xr; sumsq += xr * xr;
        }
        float mu = sum * (1.f / 128.f);
        float var = sumsq * (1.f / 128.f) - mu * mu;
        mu_s[t] = mu;
        rstd_s[t] = rsqrtf(fmaxf(var, 0.f) + 1e-5f);
        const float* vr = &Bs2[t * 48];
        float accv = 0.f;
        for (int o = 0; o < 16; ++o) {
            float mm = vr[o*3]*vr[o*3] + vr[o*3+1]*vr[o*3+1] + vr[o*3+2]*vr[o*3+2];
            accv += fmaxf(mm, 1e-8f);
        }
        vn_s[t] = sqrtf(accv * (1.f / 16.f) + 1e-5f) + 1e-5f;
    }
    __syncthreads();
    float* outF = (float*)outP;
    unsigned short* outU = (unsigned short*)outP;
    for (int idx = t; idx < NB * 128; idx += 256) {
        int ni = idx >> 7, j = idx & 127;
        int n = n0 + ni;
        if (n < N_NODES) {
            float xr = A2[ni * LDA2 + j] + A2[ni * LDA2 + 128 + j];
            float o = (xr - mu_s[ni]) * rstd_s[ni] * ldf(lngP, j, m) + ldf(lnbP, j, m);
            if (m) outF[(size_t)n * 128 + j] = o;
            else   outU[(size_t)n * 128 + j] = f2bf(o);
        }
    }
    for (int idx = t; idx < NB * 48; idx += 256) {
        int ni = idx / 48, oc = idx % 48;
        int n = n0 + ni;
        if (n < N_NODES) {
            float o = Bs2[ni * 48 + oc] / vn_s[ni];
            if (m) outF[(size_t)N_NODES * 128 + (size_t)n * 48 + oc] = o;
            else   outU[(size_t)N_NODES * 128 + (size_t)n * 48 + oc] = f2bf(o);
        }
    }
}

extern "C" void kernel_launch(void* const* d_in, const int* in_sizes, int n_in,
                              void* d_out, int out_size, void* d_ws, size_t ws_size,
                              hipStream_t stream) {
    const int* ei = (const int*)d_in[17];

    // workspace layout:
    //   [0,64)              flag
    //   [64, 200064)        cnt[N]
    //   [200064, 200128)    whwu16[16]
    //   agg_s [N*128] f32 | agg_v [N*48] f32 | perm [E] int
    //   P [N*128] f32 | Q [N*51] f32 | R [N*48] f32        (~84 MB total)
    int* flag = (int*)d_ws;
    int* cnt = (int*)((char*)d_ws + 64);
    float* whwu16 = (float*)((char*)d_ws + 64 + 200000);
    float* agg_s = (float*)((char*)d_ws + 64 + 200000 + 64);
    float* agg_v = agg_s + (size_t)N_NODES * 128;
    int* perm = (int*)(agg_v + (size_t)N_NODES * 48);
    float* Pg = (float*)(perm + E_EDGES);
    float* Qg = Pg + (size_t)N_NODES * 128;
    float* Rg = Qg + (size_t)N_NODES * 51;

    // zero flag + cnt + whwu16 + agg arrays in one contiguous memset
    hipMemsetAsync(d_ws, 0,
                   64 + 200000 + 64 + (size_t)N_NODES * (128 + 48) * sizeof(float),
                   stream);

    detect_kernel<<<1, 64, 0, stream>>>((const unsigned short*)d_in[0], flag);

    // counting sort of edges by dst
    hist_kernel<<<(E_EDGES + 255) / 256, 256, 0, stream>>>(ei, cnt);
    scan_kernel<<<1, 1024, 0, stream>>>(cnt);
    scatter_kernel<<<(E_EDGES + 255) / 256, 256, 0, stream>>>(ei, cnt, perm);

    // per-node factorization
    prep_kernel<<<(N_NODES + NB - 1) / NB, 256, 0, stream>>>(
        d_in[0], d_in[1], d_in[3], d_in[4], d_in[5], flag, Pg, Qg, Rg, whwu16);

    edge_kernel<<<E_EDGES / EB, 256, 0, stream>>>(
        d_in[2], d_in[3], d_in[5], d_in[6], d_in[7], d_in[8],
        ei, perm, flag, Pg, Qg, Rg, whwu16, agg_s, agg_v);
    node_kernel<<<(N_NODES + NB - 1) / NB, 256, 0, stream>>>(
        d_in[0], d_in[1], d_in[9], d_in[10], d_in[11], d_in[12],
        d_in[13], d_in[14], d_in[15], d_in[16], flag,
        agg_s, agg_v, d_out);
}

// Round 3
// 3817.096 us; speedup vs baseline: 1.1185x; 1.1185x over previous
//
#include <hip/hip_runtime.h>
#include <hip/hip_bf16.h>
#include <math.h>

#define N_NODES 50000
#define E_EDGES 800000
#define S_DIM 128
#define V_DIM 16
#define HM 17            // message GVP dim_h / vectors-in
#define KM 161           // 128 + 16 rbf + 17 sh
#define HU 32            // update GVP vectors-in
#define KU 288           // 256 + 32 sh

#define EB 32            // edges per tile
#define NPB 8            // dst nodes per block (CSR-partitioned)
#define LDA 164          // A-tile leading dim (161 used)
#define NB 32            // nodes per block (node kernel)
#define LDA2 292         // node A-tile leading dim (288 used)

__device__ __forceinline__ float bf2f(unsigned short u) {
    union { unsigned int i; float f; } w; w.i = ((unsigned int)u) << 16; return w.f;
}
__device__ __forceinline__ unsigned short f2bf(float f) {
    union { float f; unsigned int i; } w; w.f = f;
    unsigned int x = w.i;
    x += 0x7fff + ((x >> 16) & 1);   // round-to-nearest-even
    return (unsigned short)(x >> 16);
}
__device__ __forceinline__ float silu_f(float x) { return x / (1.f + __expf(-x)); }
__device__ __forceinline__ float sigm_f(float x) { return 1.f / (1.f + __expf(-x)); }
// scalar dual-dtype load; branch (not ternary) so neither load is speculated OOB
__device__ __forceinline__ float ldf(const void* p, int i, int m) {
    if (m) return ((const float*)p)[i];
    return bf2f(((const unsigned short*)p)[i]);
}

// ---------------------------------------------------------------------------
// Detector: fp32 (flag=1) vs bf16 (flag=0) float inputs.
// ---------------------------------------------------------------------------
__global__ void detect_kernel(const unsigned short* __restrict__ s_us,
                              int* __restrict__ flag) {
    int t = threadIdx.x;
    int huge = 0;
    for (int k = 0; k < 16; ++k) {
        unsigned short u = s_us[2 * (t + 64 * k)];
        int e = (u >> 7) & 0xFF;
        if (e > 140) huge = 1;
    }
    if (huge) atomicOr(flag, 1);
}

// ---------------------------------------------------------------------------
// Counting sort of edges by dst: histogram -> exclusive scan -> scatter.
// After scatter_kernel, cnt[n] == rowptr[n+1] (cursor ended at start+deg),
// so the edge kernel recovers rowptr[n] = (n==0 ? 0 : cnt[n-1]).
// scatter materializes src_sorted directly (no perm indirection downstream).
// ---------------------------------------------------------------------------
__global__ void hist_kernel(const int* __restrict__ ei, int* __restrict__ cnt) {
    int i = blockIdx.x * 256 + threadIdx.x;
    if (i < E_EDGES) atomicAdd(&cnt[ei[E_EDGES + i]], 1);
}

__global__ void scan_kernel(int* __restrict__ cnt) {
    __shared__ int buf[1024];
    __shared__ int base_s;
    const int t = threadIdx.x;
    if (t == 0) base_s = 0;
    __syncthreads();
    for (int c0 = 0; c0 < N_NODES; c0 += 1024) {
        int i = c0 + t;
        int v = (i < N_NODES) ? cnt[i] : 0;
        buf[t] = v;
        __syncthreads();
        for (int off = 1; off < 1024; off <<= 1) {
            int tmp = (t >= off) ? buf[t - off] : 0;
            __syncthreads();
            buf[t] += tmp;
            __syncthreads();
        }
        int base = base_s;
        if (i < N_NODES) cnt[i] = base + buf[t] - v;   // exclusive prefix
        __syncthreads();
        if (t == 0) base_s = base + buf[1023];
        __syncthreads();
    }
}

__global__ void scatter_kernel(const int* __restrict__ ei,
                               int* __restrict__ cnt,
                               int* __restrict__ src_sorted) {
    int i = blockIdx.x * 256 + threadIdx.x;
    if (i < E_EDGES) {
        int d = ei[E_EDGES + i];
        int p = atomicAdd(&cnt[d], 1);
        src_sorted[p] = ei[i];
    }
}

// ---------------------------------------------------------------------------
// Fused edge+aggregate kernel. Each block owns NPB consecutive dst nodes
// (CSR range via cnt-as-rowptr), processes their edges in 32-edge tiles with
// the round-1 message pipeline, accumulates agg_s/agg_v in LDS (race-free
// column ownership), then writes them with plain coalesced stores.
// ZERO global atomics.
// ---------------------------------------------------------------------------
__global__ __launch_bounds__(256, 4) void edge_kernel(
    const void* sP, const void* vP, const void* xP,
    const void* WhP, const void* WuP, const void* WfP,
    const void* bfP, const void* WgP, const void* bgP,
    const int* __restrict__ cnt,             // post-scatter: cnt[n] = rowptr[n+1]
    const int* __restrict__ src_sorted,
    const int* __restrict__ flagp,
    float* __restrict__ agg_s,               // [N][128]
    float* __restrict__ agg_v)               // [N][48]
{
    __shared__ float A[EB * LDA];        // 20992 B: 0..127 s->feats, 128..143 rbf, 144..160 sh
    __shared__ float Bs[2048];           // 8192 B: vin [32][52] + Wu@1664 | Wf chunks | Wg | mv
    __shared__ float WhS[HM * HM];       // 1156 B (persistent across tiles)
    __shared__ float WhWu[HM * 16];      // 1088 B
    __shared__ float gates[EB * 16];     // 2048 B
    __shared__ float aggs_ls[NPB * 128]; // 4096 B
    __shared__ float aggv_ls[NPB * 48];  // 1536 B
    __shared__ int srcb[EB], dstb[EB], dloc[EB];   // 384 B
    __shared__ int rp_s[NPB + 1];        // 36 B

    const int t = threadIdx.x;
    const int n0 = blockIdx.x * NPB;
    const int m = flagp[0];              // 1 = fp32 inputs

    // rowptr window (tail-clamped: nodes >= N get empty ranges)
    if (t <= NPB) {
        int n = n0 + t;
        if (n > N_NODES) n = N_NODES;
        rp_s[t] = (n == 0) ? 0 : cnt[n - 1];
    }
    // stage Wh -> WhS (persistent), Wu -> Bs[1664..1935] (consumed by WhWu)
    if (m) {
        const float* Wh = (const float*)WhP;
        const float* Wu = (const float*)WuP;
        for (int i = t; i < HM * HM; i += 256) WhS[i] = Wh[i];
        for (int i = t; i < HM * 16; i += 256) Bs[1664 + i] = Wu[i];
    } else {
        const unsigned short* Wh = (const unsigned short*)WhP;
        const unsigned short* Wu = (const unsigned short*)WuP;
        for (int i = t; i < HM * HM; i += 256) WhS[i] = bf2f(Wh[i]);
        for (int i = t; i < HM * 16; i += 256) Bs[1664 + i] = bf2f(Wu[i]);
    }
    // zero LDS accumulators
    for (int i = t; i < NPB * 128; i += 256) aggs_ls[i] = 0.f;
    for (int i = t; i < NPB * 48; i += 256) aggv_ls[i] = 0.f;
    __syncthreads();

    // WhWu = Wh @ Wu  [17][16] (once per block)
    for (int idx = t; idx < HM * 16; idx += 256) {
        int vv = idx / 16, o = idx % 16;
        float acc = 0.f;
        for (int h = 0; h < HM; ++h)
            acc += WhS[vv * HM + h] * Bs[1664 + h * 16 + o];
        WhWu[idx] = acc;
    }

    const int eBase = rp_s[0];
    const int eTot = rp_s[NPB] - rp_s[0];
    const int ntiles = (eTot + EB - 1) / EB;

    // bias registers persist across tiles
    const int tj = t & 15, te = t >> 4;
    const int eb = te * 2;
    float breg[8];
    #pragma unroll
    for (int jj = 0; jj < 8; ++jj) breg[jj] = ldf(bfP, tj + 16 * jj, m);

    __syncthreads();   // WhWu ready; Wu stash dead

    for (int tile = 0; tile < ntiles; ++tile) {
        const int ecnt = min(EB, eTot - tile * EB);

        // tile indices: src (coalesced), dst via rowptr-window search
        if (t < EB) {
            if (t < ecnt) {
                int p = eBase + tile * EB + t;
                srcb[t] = src_sorted[p];
                int dl = 0;
                while (dl < NPB - 1 && rp_s[dl + 1] <= p) ++dl;
                dloc[t] = dl;
                dstb[t] = n0 + dl;
            } else {
                srcb[t] = 0; dloc[t] = 0; dstb[t] = 0;
            }
        }
        __syncthreads();

        // phase 1a: gather s[src] rows into A cols 0..127
        {
            int cj = t & 31, ce = t >> 5;     // ce 0..7
            if (m) {
                const float* sF = (const float*)sP;
                for (int r = 0; r < 4; ++r) {
                    int e = ce + 8 * r;
                    float4 u = *(const float4*)(sF + (size_t)srcb[e] * S_DIM + cj * 4);
                    float* a = &A[e * LDA + cj * 4];
                    a[0] = u.x; a[1] = u.y; a[2] = u.z; a[3] = u.w;
                }
            } else {
                const unsigned short* sU = (const unsigned short*)sP;
                for (int r = 0; r < 4; ++r) {
                    int e = ce + 8 * r;
                    ushort4 u = *(const ushort4*)(sU + (size_t)srcb[e] * S_DIM + cj * 4);
                    float* a = &A[e * LDA + cj * 4];
                    a[0] = bf2f(u.x); a[1] = bf2f(u.y); a[2] = bf2f(u.z); a[3] = bf2f(u.w);
                }
            }
        }
        // phase 1b: vin into Bs[e][52] (48 = v[src], 48..50 = unit) + geometry/rbf
        if (t < 128) {
            int e = t >> 2, q = t & 3;
            int src = srcb[e];
            float* vin = &Bs[e * 52 + q * 12];
            if (m) {
                const float* vp = (const float*)vP + (size_t)src * 48 + q * 12;
                for (int i = 0; i < 3; ++i) {
                    float4 u = *(const float4*)(vp + i * 4);
                    vin[i * 4 + 0] = u.x; vin[i * 4 + 1] = u.y;
                    vin[i * 4 + 2] = u.z; vin[i * 4 + 3] = u.w;
                }
            } else {
                const unsigned short* vp = (const unsigned short*)vP + (size_t)src * 48 + q * 12;
                for (int i = 0; i < 3; ++i) {
                    ushort4 u = *(const ushort4*)(vp + i * 4);
                    vin[i * 4 + 0] = bf2f(u.x); vin[i * 4 + 1] = bf2f(u.y);
                    vin[i * 4 + 2] = bf2f(u.z); vin[i * 4 + 3] = bf2f(u.w);
                }
            }
            if (q == 0) {
                int dst = dstb[e];
                float dxc[3]; float d2 = 0.f;
                for (int c = 0; c < 3; ++c) {
                    float xs = ldf(xP, src * 3 + c, m);
                    float xd = ldf(xP, dst * 3 + c, m);
                    dxc[c] = xd - xs; d2 += dxc[c] * dxc[c];
                }
                float dist = sqrtf(fmaxf(d2, 1e-8f));
                float inv = 1.f / dist;
                for (int c = 0; c < 3; ++c) Bs[e * 52 + 48 + c] = dxc[c] * inv;
                for (int k = 0; k < 16; ++k) {
                    float mu = (20.f / 15.f) * (float)k;
                    float z = (dist - mu) * (1.f / 1.25f);
                    A[e * LDA + 128 + k] = __expf(-z * z);
                }
            }
        }
        __syncthreads();

        // phase 1c: sh[e][h] = || sum_v vin[v]*Wh[v,h] ||  -> A cols 144..160
        for (int idx = t; idx < EB * HM; idx += 256) {
            int e = idx / HM, h = idx % HM;
            const float* vin = &Bs[e * 52];
            float vh0 = 0.f, vh1 = 0.f, vh2 = 0.f;
            for (int vv = 0; vv < HM; ++vv) {
                float w = WhS[vv * HM + h];
                vh0 += vin[vv * 3 + 0] * w;
                vh1 += vin[vv * 3 + 1] * w;
                vh2 += vin[vv * 3 + 2] * w;
            }
            A[e * LDA + 144 + h] = sqrtf(fmaxf(vh0 * vh0 + vh1 * vh1 + vh2 * vh2, 1e-8f));
        }
        // phase 1d: Vu[e][o][c] into registers (6 per thread, flat 32*48)
        float vureg[6];
        for (int r = 0; r < 6; ++r) {
            int idx = t + 256 * r;
            int e = idx / 48, oc = idx % 48, o = oc / 3, c = oc % 3;
            const float* vin = &Bs[e * 52];
            float acc = 0.f;
            for (int vv = 0; vv < HM; ++vv)
                acc += vin[vv * 3 + c] * WhWu[vv * 16 + o];
            vureg[r] = acc;
        }
        __syncthreads();   // Bs free; A complete

        // phase 2: GEMM feats[32][128] = A[32][161] @ Wf[161][128]
        float acc[2][8];
        #pragma unroll
        for (int i = 0; i < 2; ++i)
            #pragma unroll
            for (int j = 0; j < 8; ++j) acc[i][j] = 0.f;

        for (int kk = 0; kk < KM; kk += 16) {
            int kmax = min(16, KM - kk);
            if (m) {
                const float* WfF = (const float*)WfP;
                for (int idx = t; idx < kmax * 32; idx += 256) {
                    int kt = idx >> 5, col4 = (idx & 31) * 4;
                    float4 u = *(const float4*)(WfF + (size_t)(kk + kt) * 128 + col4);
                    float* b = &Bs[kt * 128 + col4];
                    b[0] = u.x; b[1] = u.y; b[2] = u.z; b[3] = u.w;
                }
            } else {
                const unsigned short* WfU = (const unsigned short*)WfP;
                for (int idx = t; idx < kmax * 32; idx += 256) {
                    int kt = idx >> 5, col4 = (idx & 31) * 4;
                    ushort4 u = *(const ushort4*)(WfU + (size_t)(kk + kt) * 128 + col4);
                    float* b = &Bs[kt * 128 + col4];
                    b[0] = bf2f(u.x); b[1] = bf2f(u.y); b[2] = bf2f(u.z); b[3] = bf2f(u.w);
                }
            }
            __syncthreads();
            for (int kt = 0; kt < kmax; ++kt) {
                float a0 = A[(eb + 0) * LDA + kk + kt];
                float a1 = A[(eb + 1) * LDA + kk + kt];
                const float* brow = &Bs[kt * 128 + tj];
                #pragma unroll
                for (int jj = 0; jj < 8; ++jj) {
                    float b = brow[16 * jj];
                    acc[0][jj] += a0 * b; acc[1][jj] += a1 * b;
                }
            }
            __syncthreads();
        }
        // bias + silu -> feats into A cols 0..127
        #pragma unroll
        for (int i = 0; i < 2; ++i) {
            float* aout = &A[(eb + i) * LDA];
            #pragma unroll
            for (int jj = 0; jj < 8; ++jj)
                aout[tj + 16 * jj] = silu_f(acc[i][jj] + breg[jj]);
        }
        __syncthreads();
        // stage Wg [128][16] -> Bs[0..2047]
        if (m) {
            const float* Wg = (const float*)WgP;
            for (int i = t; i < 2048; i += 256) Bs[i] = Wg[i];
        } else {
            const unsigned short* Wg = (const unsigned short*)WgP;
            for (int i = t; i < 2048; i += 256) Bs[i] = bf2f(Wg[i]);
        }
        __syncthreads();
        // phase 3: gates[e][o] = sigmoid(feats @ Wg + bg)
        for (int r = 0; r < 2; ++r) {
            int idx = t + 256 * r;
            int e = idx / 16, o = idx % 16;
            const float* fe = &A[e * LDA];
            float g = ldf(bgP, o, m);
            for (int j = 0; j < S_DIM; ++j)
                g += fe[j] * Bs[j * 16 + o];
            gates[idx] = sigm_f(g);
        }
        __syncthreads();
        // phase 4: mv = gate * Vu -> Bs[0..1535] (Wg stash dead)
        for (int r = 0; r < 6; ++r) {
            int idx = t + 256 * r;               // idx == e*48 + oc
            int e = idx / 48, oc = idx % 48, o = oc / 3;
            (void)oc;
            Bs[idx] = vureg[r] * gates[e * 16 + o];
        }
        __syncthreads();
        // phase 5: accumulate into LDS agg (column ownership -> race-free)
        if (t < 176) {
            if (t < 128) {
                const int col = t;
                for (int e = 0; e < ecnt; ++e)
                    aggs_ls[dloc[e] * 128 + col] += A[e * LDA + col];
            } else {
                const int oc = t - 128;
                for (int e = 0; e < ecnt; ++e)
                    aggv_ls[dloc[e] * 48 + oc] += Bs[e * 48 + oc];
            }
        }
        __syncthreads();   // before next tile clobbers A/Bs
    }

    // write aggregates (plain coalesced stores; covers zero-degree nodes too)
    for (int idx = t; idx < NPB * 128; idx += 256) {
        int n = n0 + (idx >> 7);
        if (n < N_NODES) agg_s[(size_t)n * 128 + (idx & 127)] = aggs_ls[idx];
    }
    for (int idx = t; idx < NPB * 48; idx += 256) {
        int n = n0 + idx / 48;
        if (n < N_NODES) agg_v[(size_t)n * 48 + idx % 48] = aggv_ls[idx];
    }
}

// ---------------------------------------------------------------------------
// Node (update) kernel: per block, 32 nodes. Update GVP + residual + LN.
// (unchanged)
// ---------------------------------------------------------------------------
__global__ __launch_bounds__(256) void node_kernel(
    const void* sP, const void* vP,
    const void* WhP, const void* WuP, const void* WfP,
    const void* bfP, const void* WgP, const void* bgP,
    const void* lngP, const void* lnbP,
    const int* __restrict__ flagp,
    const float* __restrict__ agg_s,         // [N][128]
    const float* __restrict__ agg_v,         // [N][48]
    void* outP)                              // [N*128] then [N*48]
{
    __shared__ float A2[NB * LDA2];
    __shared__ float Bs2[4096];
    __shared__ float WhWu2[HU * 16];
    __shared__ float gates2[NB * 16];
    __shared__ float WhS[HU * HU];
    __shared__ float mu_s[NB], rstd_s[NB], vn_s[NB];

    const int t = threadIdx.x;
    const int n0 = blockIdx.x * NB;
    const int m = flagp[0];

    if (m) {
        const float* Wh = (const float*)WhP;
        const float* Wu = (const float*)WuP;
        for (int i = t; i < HU * HU; i += 256) WhS[i] = Wh[i];
        for (int i = t; i < HU * 16; i += 256) gates2[i] = Wu[i];
    } else {
        const unsigned short* Wh = (const unsigned short*)WhP;
        const unsigned short* Wu = (const unsigned short*)WuP;
        for (int i = t; i < HU * HU; i += 256) WhS[i] = bf2f(Wh[i]);
        for (int i = t; i < HU * 16; i += 256) gates2[i] = bf2f(Wu[i]);
    }
    if (m) {
        const float* sF = (const float*)sP;
        for (int idx = t; idx < NB * 32; idx += 256) {
            int ni = idx >> 5, col4 = (idx & 31) * 4;
            int n = n0 + ni;
            float* a = &A2[ni * LDA2 + col4];
            if (n < N_NODES) {
                float4 u = *(const float4*)(sF + (size_t)n * 128 + col4);
                a[0] = u.x; a[1] = u.y; a[2] = u.z; a[3] = u.w;
            } else { a[0] = a[1] = a[2] = a[3] = 0.f; }
        }
    } else {
        const unsigned short* sU = (const unsigned short*)sP;
        for (int idx = t; idx < NB * 32; idx += 256) {
            int ni = idx >> 5, col4 = (idx & 31) * 4;
            int n = n0 + ni;
            float* a = &A2[ni * LDA2 + col4];
            if (n < N_NODES) {
                ushort4 u = *(const ushort4*)(sU + (size_t)n * 128 + col4);
                a[0] = bf2f(u.x); a[1] = bf2f(u.y); a[2] = bf2f(u.z); a[3] = bf2f(u.w);
            } else { a[0] = a[1] = a[2] = a[3] = 0.f; }
        }
    }
    for (int idx = t; idx < NB * 32; idx += 256) {
        int ni = idx >> 5, col4 = (idx & 31) * 4;
        int n = n0 + ni;
        float* a = &A2[ni * LDA2 + 128 + col4];
        if (n < N_NODES) {
            float4 u = *(const float4*)(agg_s + (size_t)n * 128 + col4);
            a[0] = u.x * 0.1f; a[1] = u.y * 0.1f; a[2] = u.z * 0.1f; a[3] = u.w * 0.1f;
        } else { a[0] = a[1] = a[2] = a[3] = 0.f; }
    }
    for (int idx = t; idx < NB * 96; idx += 256) {
        int ni = idx / 96, vc = idx % 96;
        int n = n0 + ni;
        float val = 0.f;
        if (n < N_NODES)
            val = (vc < 48) ? ldf(vP, n * 48 + vc, m)
                            : agg_v[(size_t)n * 48 + (vc - 48)] * 0.1f;
        Bs2[ni * 100 + vc] = val;
    }
    __syncthreads();
    for (int idx = t; idx < HU * 16; idx += 256) {
        int vv = idx / 16, o = idx % 16;
        float acc = 0.f;
        for (int h = 0; h < HU; ++h)
            acc += WhS[vv * HU + h] * gates2[h * 16 + o];
        WhWu2[idx] = acc;
    }
    for (int idx = t; idx < NB * HU; idx += 256) {
        int ni = idx / HU, h = idx % HU;
        const float* vc = &Bs2[ni * 100];
        float vh0 = 0.f, vh1 = 0.f, vh2 = 0.f;
        for (int vv = 0; vv < HU; ++vv) {
            float w = WhS[vv * HU + h];
            vh0 += vc[vv * 3 + 0] * w; vh1 += vc[vv * 3 + 1] * w; vh2 += vc[vv * 3 + 2] * w;
        }
        A2[ni * LDA2 + 256 + h] = sqrtf(fmaxf(vh0 * vh0 + vh1 * vh1 + vh2 * vh2, 1e-8f));
    }
    __syncthreads();
    float vureg[6];
    for (int r = 0; r < 6; ++r) {
        int idx = t + 256 * r;
        int ni = idx / 48, oc = idx % 48, o = oc / 3, c = oc % 3;
        const float* vc = &Bs2[ni * 100];
        float acc = 0.f;
        for (int vv = 0; vv < HU; ++vv)
            acc += vc[vv * 3 + c] * WhWu2[vv * 16 + o];
        vureg[r] = acc;
    }
    __syncthreads();

    const int tj = t & 15, tn = t >> 4;
    const int nb = tn * 2;
    float acc[2][8];
    #pragma unroll
    for (int i = 0; i < 2; ++i)
        #pragma unroll
        for (int j = 0; j < 8; ++j) acc[i][j] = 0.f;

    for (int kk = 0; kk < KU; kk += 32) {
        if (m) {
            const float* WfF = (const float*)WfP;
            for (int idx = t; idx < 32 * 32; idx += 256) {
                int kt = idx >> 5, col4 = (idx & 31) * 4;
                float4 u = *(const float4*)(WfF + (size_t)(kk + kt) * 128 + col4);
                float* b = &Bs2[kt * 128 + col4];
                b[0] = u.x; b[1] = u.y; b[2] = u.z; b[3] = u.w;
            }
        } else {
            const unsigned short* WfU = (const unsigned short*)WfP;
            for (int idx = t; idx < 32 * 32; idx += 256) {
                int kt = idx >> 5, col4 = (idx & 31) * 4;
                ushort4 u = *(const ushort4*)(WfU + (size_t)(kk + kt) * 128 + col4);
                float* b = &Bs2[kt * 128 + col4];
                b[0] = bf2f(u.x); b[1] = bf2f(u.y); b[2] = bf2f(u.z); b[3] = bf2f(u.w);
            }
        }
        __syncthreads();
        for (int kt = 0; kt < 32; ++kt) {
            float a0 = A2[(nb + 0) * LDA2 + kk + kt];
            float a1 = A2[(nb + 1) * LDA2 + kk + kt];
            const float* brow = &Bs2[kt * 128 + tj];
            #pragma unroll
            for (int jj = 0; jj < 8; ++jj) {
                float b = brow[16 * jj];
                acc[0][jj] += a0 * b; acc[1][jj] += a1 * b;
            }
        }
        __syncthreads();
    }
    float breg[8];
    #pragma unroll
    for (int jj = 0; jj < 8; ++jj) breg[jj] = ldf(bfP, tj + 16 * jj, m);
    #pragma unroll
    for (int i = 0; i < 2; ++i) {
        float* aout = &A2[(nb + i) * LDA2 + 128];
        #pragma unroll
        for (int jj = 0; jj < 8; ++jj)
            aout[tj + 16 * jj] = silu_f(acc[i][jj] + breg[jj]);
    }
    __syncthreads();
    if (m) {
        const float* Wg = (const float*)WgP;
        for (int i = t; i < 2048; i += 256) Bs2[i] = Wg[i];
    } else {
        const unsigned short* Wg = (const unsigned short*)WgP;
        for (int i = t; i < 2048; i += 256) Bs2[i] = bf2f(Wg[i]);
    }
    __syncthreads();
    for (int r = 0; r < 2; ++r) {
        int idx = t + 256 * r;
        int ni = idx / 16, o = idx % 16;
        const float* fe = &A2[ni * LDA2 + 128];
        float g = ldf(bgP, o, m);
        for (int j = 0; j < 128; ++j)
            g += fe[j] * Bs2[j * 16 + o];
        gates2[idx] = sigm_f(g);
    }
    __syncthreads();
    for (int r = 0; r < 6; ++r) {
        int idx = t + 256 * r;
        int ni = idx / 48, oc = idx % 48, o = oc / 3;
        int n = n0 + ni;
        float vres = 0.f;
        if (n < N_NODES)
            vres = ldf(vP, n * 48 + oc, m) + vureg[r] * gates2[ni * 16 + o];
        Bs2[ni * 48 + oc] = vres;
    }
    __syncthreads();
    if (t < NB) {
        const float* arow = &A2[t * LDA2];
        float sum = 0.f, sumsq = 0.f;
        for (int j = 0; j < 128; ++j) {
            float xr = arow[j] + arow[128 + j];
            sum += xr; sumsq += xr * xr;
        }
        float mu = sum * (1.f / 128.f);
        float var = sumsq * (1.f / 128.f) - mu * mu;
        mu_s[t] = mu;
        rstd_s[t] = rsqrtf(fmaxf(var, 0.f) + 1e-5f);
        const float* vr = &Bs2[t * 48];
        float accv = 0.f;
        for (int o = 0; o < 16; ++o) {
            float mm = vr[o*3]*vr[o*3] + vr[o*3+1]*vr[o*3+1] + vr[o*3+2]*vr[o*3+2];
            accv += fmaxf(mm, 1e-8f);
        }
        vn_s[t] = sqrtf(accv * (1.f / 16.f) + 1e-5f) + 1e-5f;
    }
    __syncthreads();
    float* outF = (float*)outP;
    unsigned short* outU = (unsigned short*)outP;
    for (int idx = t; idx < NB * 128; idx += 256) {
        int ni = idx >> 7, j = idx & 127;
        int n = n0 + ni;
        if (n < N_NODES) {
            float xr = A2[ni * LDA2 + j] + A2[ni * LDA2 + 128 + j];
            float o = (xr - mu_s[ni]) * rstd_s[ni] * ldf(lngP, j, m) + ldf(lnbP, j, m);
            if (m) outF[(size_t)n * 128 + j] = o;
            else   outU[(size_t)n * 128 + j] = f2bf(o);
        }
    }
    for (int idx = t; idx < NB * 48; idx += 256) {
        int ni = idx / 48, oc = idx % 48;
        int n = n0 + ni;
        if (n < N_NODES) {
            float o = Bs2[ni * 48 + oc] / vn_s[ni];
            if (m) outF[(size_t)N_NODES * 128 + (size_t)n * 48 + oc] = o;
            else   outU[(size_t)N_NODES * 128 + (size_t)n * 48 + oc] = f2bf(o);
        }
    }
}

extern "C" void kernel_launch(void* const* d_in, const int* in_sizes, int n_in,
                              void* d_out, int out_size, void* d_ws, size_t ws_size,
                              hipStream_t stream) {
    const int* ei = (const int*)d_in[17];

    // workspace layout:
    //   [0,64)        flag
    //   [64,200064)   cnt[N] (counts -> offsets -> cursors; post-scatter = rowptr[n+1])
    //   src_sorted [E] int | agg_s [N*128] f32 | agg_v [N*48] f32
    int* flag = (int*)d_ws;
    int* cnt = (int*)((char*)d_ws + 64);
    int* src_sorted = (int*)((char*)d_ws + 64 + 200000);
    float* agg_s = (float*)(src_sorted + E_EDGES);
    float* agg_v = agg_s + (size_t)N_NODES * 128;

    // zero flag + cnt only (agg arrays fully written by edge_kernel)
    hipMemsetAsync(d_ws, 0, 64 + 200000, stream);

    detect_kernel<<<1, 64, 0, stream>>>((const unsigned short*)d_in[0], flag);

    // counting sort of edges by dst
    hist_kernel<<<(E_EDGES + 255) / 256, 256, 0, stream>>>(ei, cnt);
    scan_kernel<<<1, 1024, 0, stream>>>(cnt);
    scatter_kernel<<<(E_EDGES + 255) / 256, 256, 0, stream>>>(ei, cnt, src_sorted);

    edge_kernel<<<(N_NODES + NPB - 1) / NPB, 256, 0, stream>>>(
        d_in[0], d_in[1], d_in[2], d_in[3], d_in[4], d_in[5],
        d_in[6], d_in[7], d_in[8], cnt, src_sorted, flag, agg_s, agg_v);
    node_kernel<<<(N_NODES + NB - 1) / NB, 256, 0, stream>>>(
        d_in[0], d_in[1], d_in[9], d_in[10], d_in[11], d_in[12],
        d_in[13], d_in[14], d_in[15], d_in[16], flag,
        agg_s, agg_v, d_out);
}